// Round 2
// 115.083 us; speedup vs baseline: 1.0218x; 1.0218x over previous
//
#include <hip/hip_runtime.h>

typedef short bf16x8 __attribute__((ext_vector_type(8)));   // 8 bf16 in 4 VGPRs
typedef float f32x4v __attribute__((ext_vector_type(4)));

// ---- constants derived from the reference ----
// grid = linspace(-1,1,12); centers c_k = -1 + (3+k)*2/11, k=0..7
// h = 0.4 + 1e-6 ; z_k = (x - c_k)/h = u - k*DLT,  u = (x - c0)/h
// basis_k = exp(-z_k^2/2) = exp2(A2*u^2) * exp2(B2*u)^k * exp2(GCF*k^2)
// exp2(GCF*k^2) is constant per k and folded into the weights at prep time.
constexpr double H_D    = 0.4 + 1e-6;
constexpr double INVH_D = 1.0 / H_D;
constexpr double C0_D   = -1.0 + 6.0 / 11.0;
constexpr double DLT_D  = (2.0 / 11.0) / H_D;
constexpr double L2E_D  = 1.4426950408889634;

constexpr float INVH = (float)INVH_D;
constexpr float NC0H = (float)(-C0_D * INVH_D);           // u = x*INVH + NC0H
constexpr float A2f  = (float)(-0.5 * L2E_D);             // E0 = exp2(A2*u*u)
constexpr float B2f  = (float)(DLT_D * L2E_D);            // r  = exp2(B2*u)
constexpr float GCF  = (float)(-0.5 * DLT_D * DLT_D * L2E_D); // g_k = exp2(GCF*k*k)
constexpr float NL2E = (float)(-L2E_D);

__device__ __forceinline__ float fexp2(float v) {
#if __has_builtin(__builtin_amdgcn_exp2f)
  return __builtin_amdgcn_exp2f(v);
#else
  return exp2f(v);
#endif
}
__device__ __forceinline__ float frcp(float v) {
#if __has_builtin(__builtin_amdgcn_rcpf)
  return __builtin_amdgcn_rcpf(v);
#else
  return 1.0f / v;
#endif
}
__device__ __forceinline__ float siluf(float v) {
  // v * sigmoid(v) = v / (1 + 2^(-log2e * v))
  return v * frcp(1.0f + fexp2(NL2E * v));
}
// single-instruction packed f32x2 -> bf16x2 (gfx950 v_cvt_pk_bf16_f32, RNE).
// D[15:0] = cvt(S0)=lo, D[31:16] = cvt(S1)=hi -> element order matches frag.
__device__ __forceinline__ unsigned pkbf(float lo, float hi) {
  unsigned r;
  asm("v_cvt_pk_bf16_f32 %0, %1, %2" : "=v"(r) : "v"(lo), "v"(hi));
  return r;
}
__device__ __forceinline__ bf16x8 packfrag(const float (&v)[8]) {
  uint4 d;
  d.x = pkbf(v[0], v[1]);
  d.y = pkbf(v[2], v[3]);
  d.z = pkbf(v[4], v[5]);
  d.w = pkbf(v[6], v[7]);
  return __builtin_bit_cast(bf16x8, d);
}
// RNE fp32 -> bf16 (prep path)
__device__ __forceinline__ unsigned rne16(float f) {
  unsigned u = __float_as_uint(f);
  return (u + 0x7fffu + ((u >> 16) & 1u)) >> 16;
}

// ---------------- prep: build fragment-ordered bf16 weights + bias ----------------
// K ordering: k = G*288 + t*32 + c   (G=0..3 channel-groups of 32, t=0..8 feature,
//                                     c = quad*8 + j channel within group)
// Fragment entry e = (G*9+t)*2 + h  (h = column half), lane l: col n = h*16 + (l&15),
// channels cbase = G*32 + (l>>4)*8 + (0..7)  -> matches MFMA B[k=quad*8+j][n=lane&15].
__global__ void kan_prep(const float* __restrict__ coeff,
                         const float* __restrict__ bw,
                         const float* __restrict__ bb,
                         const float* __restrict__ ew,
                         uint4* __restrict__ wfrag,
                         float* __restrict__ bias) {
  if (blockIdx.x == 18) {
    // bias[n] = sum_i ew[i][n]*bb[i][n]; 256 thr = 32 n × 8 chunks of 16 i
    __shared__ float part[256];
    const int n = threadIdx.x & 31;
    const int c = threadIdx.x >> 5;
    float s = 0.f;
#pragma unroll
    for (int i = c * 16; i < c * 16 + 16; ++i)
      s += ew[i * 32 + n] * bb[i * 32 + n];
    part[threadIdx.x] = s;
    __syncthreads();
    if (threadIdx.x < 32) {
      float t = 0.f;
#pragma unroll
      for (int c2 = 0; c2 < 8; ++c2) t += part[c2 * 32 + threadIdx.x];
      bias[threadIdx.x] = t;
    }
    return;
  }
  const int e    = blockIdx.x * 4 + (threadIdx.x >> 6); // 0..71  (= s*2 + h)
  const int lane = threadIdx.x & 63;
  const int s = e >> 1, h = e & 1;
  const int G = s / 9, t = s % 9;
  const int n = h * 16 + (lane & 15);
  const int cbase = G * 32 + (lane >> 4) * 8;
  float v[8];
  if (t == 0) {
#pragma unroll
    for (int j = 0; j < 8; ++j) {
      int i = cbase + j;
      v[j] = ew[i * 32 + n] * bw[i * 32 + n];
    }
  } else {
    const int k = t - 1;
    const float g = exp2f(GCF * (float)(k * k)); // fold g_k into weight
#pragma unroll
    for (int j = 0; j < 8; ++j) {
      int i = cbase + j;
      v[j] = ew[i * 32 + n] * coeff[(i * 32 + n) * 8 + k] * g;
    }
  }
  uint4 d;
  d.x = (rne16(v[1]) << 16) | rne16(v[0]);
  d.y = (rne16(v[3]) << 16) | rne16(v[2]);
  d.z = (rne16(v[5]) << 16) | rne16(v[4]);
  d.w = (rne16(v[7]) << 16) | rne16(v[6]);
  wfrag[e * 64 + lane] = d;
}

// async global->LDS, 16B per lane; LDS layout must be base + lane*16 (it is:
// dest index = tid + i*256 -> per wave: wave-uniform base + lane*16).
__device__ __forceinline__ void gl_lds16(const uint4* g, uint4* l) {
  __builtin_amdgcn_global_load_lds(
      (const __attribute__((address_space(1))) void*)g,
      (__attribute__((address_space(3))) void*)l, 16, 0, 0);
}

__device__ __forceinline__ void ld8(const float* p, float (&v)[8]) {
  const float4* q = reinterpret_cast<const float4*>(p);
  float4 a = q[0], b = q[1];
  v[0] = a.x; v[1] = a.y; v[2] = a.z; v[3] = a.w;
  v[4] = b.x; v[5] = b.y; v[6] = b.z; v[7] = b.w;
}

// ---------------- main: fused feature-gen + MFMA GEMM ----------------
// TWO row-tiles (32 rows) per wave so every weight ds_read_b128 feeds 2 MFMAs
// and per-row LDS/staging traffic halves. 256-thr blocks, 4 blocks/CU
// (16 waves/CU, 128 VGPR cap). Weights double-buffered in LDS (2 x 18.4 KB):
// global_load_lds for G+1 overlaps G's compute; ONE barrier per G (the
// end-of-iteration __syncthreads both drains the staging vmcnt and orders
// buffer reuse), instead of the old stage->drain->compute 2-barrier shape.
__global__ __launch_bounds__(256, 4) void kan_main(
    const float* __restrict__ x,
    const uint4* __restrict__ wfrag,
    const float* __restrict__ bias,
    float* __restrict__ out) {
  __shared__ uint4 wlds[2][1152];  // double-buffered: 18 frag-entries * 64 lanes
  const int tid  = threadIdx.x;
  const int lane = tid & 63;
  const int wave = tid >> 6;
  const int m    = lane & 15;  // A row-in-tile; also C/D column (within half)
  const int quad = lane >> 4;  // A channel-octet selector; C/D row group
  const long rowbase = ((long)blockIdx.x * 4 + wave) * 32;

  f32x4v a0A, a1A, a0B, a1B;
#pragma unroll
  for (int rr = 0; rr < 4; ++rr) {
    a0A[rr] = 0.f; a1A[rr] = 0.f; a0B[rr] = 0.f; a1B[rr] = 0.f;
  }

  // per-lane x base: tile A = rows rowbase+0..15, tile B = rows rowbase+16..31
  const float* xpA = x + (rowbase + m) * 128 + (long)quad * 8;
  const float* xpB = xpA + 16 * 128;

  float xa[8], xb[8];
  ld8(xpA, xa);
  ld8(xpB, xb);
  const float bv0 = bias[m];
  const float bv1 = bias[m + 16];

  // prologue: stage G=0 into buffer 0
  {
#pragma unroll
    for (int i = 0; i < 4; ++i)
      gl_lds16(wfrag + tid + i * 256, &wlds[0][tid + i * 256]);
    if (tid < 128) gl_lds16(wfrag + 1024 + tid, &wlds[0][1024 + tid]);
  }
  __syncthreads();  // buf0 staged (drains x loads too)

#pragma unroll 1
  for (int G = 0; G < 4; ++G) {
    // ---- issue stage of G+1 into the other buffer; completes by the
    //      end-of-iteration barrier (hidden under this G's compute) ----
    if (G < 3) {
      const uint4* src = wfrag + (size_t)(G + 1) * 1152;
      uint4* dst = &wlds[(G + 1) & 1][0];
#pragma unroll
      for (int i = 0; i < 4; ++i)
        gl_lds16(src + tid + i * 256, dst + tid + i * 256);
      if (tid < 128) gl_lds16(src + 1024 + tid, dst + 1024 + tid);
    }

    // ---- consume xa/xb into compact per-G state (both row-tiles) ----
    bf16x8 sA, sB;
    float pA[8], rA[8], pB[8], rB[8];
    {
      float sv[8];
#pragma unroll
      for (int j = 0; j < 8; ++j) sv[j] = siluf(xa[j]);
      sA = packfrag(sv);
#pragma unroll
      for (int j = 0; j < 8; ++j) sv[j] = siluf(xb[j]);
      sB = packfrag(sv);
#pragma unroll
      for (int j = 0; j < 8; ++j) {
        float u = fmaf(xa[j], INVH, NC0H);
        pA[j] = fexp2(A2f * u * u);
        rA[j] = fexp2(B2f * u);
      }
#pragma unroll
      for (int j = 0; j < 8; ++j) {
        float u = fmaf(xb[j], INVH, NC0H);
        pB[j] = fexp2(A2f * u * u);
        rB[j] = fexp2(B2f * u);
      }
    }

    // ---- prefetch next G's x (in flight across the compute; drained at
    //      the end-of-iteration barrier) ----
    if (G < 3) {
      ld8(xpA + (G + 1) * 32, xa);
      ld8(xpB + (G + 1) * 32, xb);
    }

    const uint4* wl = &wlds[G & 1][0] + lane;

    // ---- t = 0 : silu feature (both tiles share the weight frags) ----
    a0A = __builtin_amdgcn_mfma_f32_16x16x32_bf16(
        sA, __builtin_bit_cast(bf16x8, wl[0]), a0A, 0, 0, 0);
    a1A = __builtin_amdgcn_mfma_f32_16x16x32_bf16(
        sA, __builtin_bit_cast(bf16x8, wl[64]), a1A, 0, 0, 0);
    a0B = __builtin_amdgcn_mfma_f32_16x16x32_bf16(
        sB, __builtin_bit_cast(bf16x8, wl[0]), a0B, 0, 0, 0);
    a1B = __builtin_amdgcn_mfma_f32_16x16x32_bf16(
        sB, __builtin_bit_cast(bf16x8, wl[64]), a1B, 0, 0, 0);

    // ---- t = 1..8 : gaussian recurrence (g_k folded into weights) ----
#pragma unroll
    for (int t = 1; t <= 8; ++t) {
      bf16x8 c0 = __builtin_bit_cast(bf16x8, wl[t * 128]);
      bf16x8 c1 = __builtin_bit_cast(bf16x8, wl[t * 128 + 64]);
      bf16x8 fA = packfrag(pA);
      bf16x8 fB = packfrag(pB);
      a0A = __builtin_amdgcn_mfma_f32_16x16x32_bf16(fA, c0, a0A, 0, 0, 0);
      a1A = __builtin_amdgcn_mfma_f32_16x16x32_bf16(fA, c1, a1A, 0, 0, 0);
      a0B = __builtin_amdgcn_mfma_f32_16x16x32_bf16(fB, c0, a0B, 0, 0, 0);
      a1B = __builtin_amdgcn_mfma_f32_16x16x32_bf16(fB, c1, a1B, 0, 0, 0);
      if (t < 8) {
#pragma unroll
        for (int j = 0; j < 8; ++j) { pA[j] *= rA[j]; pB[j] *= rB[j]; }
      }
    }
    // one barrier per G: orders (a) this G's LDS reads before the buffer is
    // overwritten next iteration, (b) drains the G+1 staging vmcnt so the
    // next iteration can read it. Skipped on the last G (epilogue is reg-only).
    if (G < 3) __syncthreads();
  }

  // epilogue: C/D layout col = lane&15 (per half), row = quad*4 + reg
#pragma unroll
  for (int rr = 0; rr < 4; ++rr) {
    long row = rowbase + quad * 4 + rr;
    out[row * 32 + m]             = a0A[rr] + bv0;
    out[row * 32 + m + 16]        = a1A[rr] + bv1;
    out[(row + 16) * 32 + m]      = a0B[rr] + bv0;
    out[(row + 16) * 32 + m + 16] = a1B[rr] + bv1;
  }
}

extern "C" void kernel_launch(void* const* d_in, const int* in_sizes, int n_in,
                              void* d_out, int out_size, void* d_ws, size_t ws_size,
                              hipStream_t stream) {
  const float* x     = (const float*)d_in[0]; // (131072,128)
  const float* coeff = (const float*)d_in[1]; // (128,32,8)
  const float* bw    = (const float*)d_in[2]; // (128,32)
  const float* bb    = (const float*)d_in[3]; // (128,32)
  const float* ew    = (const float*)d_in[4]; // (128,32)

  uint4* wfrag = (uint4*)d_ws;                       // 72*64*16 = 73728 B
  float* bias  = (float*)((char*)d_ws + 73728);      // 32 floats

  kan_prep<<<19, 256, 0, stream>>>(coeff, bw, bb, ew, wfrag, bias);
  // 131072 rows / (4 waves * 32 rows) = 1024 blocks
  kan_main<<<1024, 256, 0, stream>>>(x, wfrag, bias, (float*)d_out);
}

// Round 3
// 113.341 us; speedup vs baseline: 1.0375x; 1.0154x over previous
//
#include <hip/hip_runtime.h>

typedef short bf16x8 __attribute__((ext_vector_type(8)));   // 8 bf16 in 4 VGPRs
typedef float f32x4v __attribute__((ext_vector_type(4)));

// ---- constants derived from the reference ----
// grid = linspace(-1,1,12); centers c_k = -1 + (3+k)*2/11, k=0..7
// h = 0.4 + 1e-6 ; z_k = (x - c_k)/h = u - k*DLT,  u = (x - c0)/h
// basis_k = exp(-z_k^2/2) = exp2(A2*u^2) * exp2(B2*u)^k * exp2(GCF*k^2)
// exp2(GCF*k^2) is constant per k and folded into the weights at prep time.
constexpr double H_D    = 0.4 + 1e-6;
constexpr double INVH_D = 1.0 / H_D;
constexpr double C0_D   = -1.0 + 6.0 / 11.0;
constexpr double DLT_D  = (2.0 / 11.0) / H_D;
constexpr double L2E_D  = 1.4426950408889634;

constexpr float INVH = (float)INVH_D;
constexpr float NC0H = (float)(-C0_D * INVH_D);           // u = x*INVH + NC0H
constexpr float A2f  = (float)(-0.5 * L2E_D);             // E0 = exp2(A2*u*u)
constexpr float B2f  = (float)(DLT_D * L2E_D);            // r  = exp2(B2*u)
constexpr float GCF  = (float)(-0.5 * DLT_D * DLT_D * L2E_D); // g_k = exp2(GCF*k*k)
constexpr float NL2E = (float)(-L2E_D);

__device__ __forceinline__ float fexp2(float v) {
#if __has_builtin(__builtin_amdgcn_exp2f)
  return __builtin_amdgcn_exp2f(v);
#else
  return exp2f(v);
#endif
}
__device__ __forceinline__ float frcp(float v) {
#if __has_builtin(__builtin_amdgcn_rcpf)
  return __builtin_amdgcn_rcpf(v);
#else
  return 1.0f / v;
#endif
}
__device__ __forceinline__ float siluf(float v) {
  // v * sigmoid(v) = v / (1 + 2^(-log2e * v))
  return v * frcp(1.0f + fexp2(NL2E * v));
}
// single-instruction packed f32x2 -> bf16x2 (gfx950 v_cvt_pk_bf16_f32, RNE).
// D[15:0] = cvt(S0)=lo, D[31:16] = cvt(S1)=hi -> element order matches frag.
__device__ __forceinline__ unsigned pkbf(float lo, float hi) {
  unsigned r;
  asm("v_cvt_pk_bf16_f32 %0, %1, %2" : "=v"(r) : "v"(lo), "v"(hi));
  return r;
}
__device__ __forceinline__ bf16x8 packfrag(const float (&v)[8]) {
  uint4 d;
  d.x = pkbf(v[0], v[1]);
  d.y = pkbf(v[2], v[3]);
  d.z = pkbf(v[4], v[5]);
  d.w = pkbf(v[6], v[7]);
  return __builtin_bit_cast(bf16x8, d);
}
// RNE fp32 -> bf16 (prep path)
__device__ __forceinline__ unsigned rne16(float f) {
  unsigned u = __float_as_uint(f);
  return (u + 0x7fffu + ((u >> 16) & 1u)) >> 16;
}

// ---------------- prep: build fragment-ordered bf16 weights + bias ----------------
// K ordering: k = G*288 + t*32 + c   (G=0..3 channel-groups of 32, t=0..8 feature,
//                                     c = quad*8 + j channel within group)
// Fragment entry e = (G*9+t)*2 + h  (h = column half), lane l: col n = h*16 + (l&15),
// channels cbase = G*32 + (l>>4)*8 + (0..7)  -> matches MFMA B[k=quad*8+j][n=lane&15].
__global__ void kan_prep(const float* __restrict__ coeff,
                         const float* __restrict__ bw,
                         const float* __restrict__ bb,
                         const float* __restrict__ ew,
                         uint4* __restrict__ wfrag,
                         float* __restrict__ bias) {
  if (blockIdx.x == 18) {
    // bias[n] = sum_i ew[i][n]*bb[i][n]; 256 thr = 32 n × 8 chunks of 16 i
    __shared__ float part[256];
    const int n = threadIdx.x & 31;
    const int c = threadIdx.x >> 5;
    float s = 0.f;
#pragma unroll
    for (int i = c * 16; i < c * 16 + 16; ++i)
      s += ew[i * 32 + n] * bb[i * 32 + n];
    part[threadIdx.x] = s;
    __syncthreads();
    if (threadIdx.x < 32) {
      float t = 0.f;
#pragma unroll
      for (int c2 = 0; c2 < 8; ++c2) t += part[c2 * 32 + threadIdx.x];
      bias[threadIdx.x] = t;
    }
    return;
  }
  const int e    = blockIdx.x * 4 + (threadIdx.x >> 6); // 0..71  (= s*2 + h)
  const int lane = threadIdx.x & 63;
  const int s = e >> 1, h = e & 1;
  const int G = s / 9, t = s % 9;
  const int n = h * 16 + (lane & 15);
  const int cbase = G * 32 + (lane >> 4) * 8;
  float v[8];
  if (t == 0) {
#pragma unroll
    for (int j = 0; j < 8; ++j) {
      int i = cbase + j;
      v[j] = ew[i * 32 + n] * bw[i * 32 + n];
    }
  } else {
    const int k = t - 1;
    const float g = exp2f(GCF * (float)(k * k)); // fold g_k into weight
#pragma unroll
    for (int j = 0; j < 8; ++j) {
      int i = cbase + j;
      v[j] = ew[i * 32 + n] * coeff[(i * 32 + n) * 8 + k] * g;
    }
  }
  uint4 d;
  d.x = (rne16(v[1]) << 16) | rne16(v[0]);
  d.y = (rne16(v[3]) << 16) | rne16(v[2]);
  d.z = (rne16(v[5]) << 16) | rne16(v[4]);
  d.w = (rne16(v[7]) << 16) | rne16(v[6]);
  wfrag[e * 64 + lane] = d;
}

// async global->LDS, 16B per lane; LDS layout must be base + lane*16 (it is:
// dest index = tid + i*512 -> per wave: wave-uniform base + lane*16).
__device__ __forceinline__ void gl_lds16(const uint4* g, uint4* l) {
  __builtin_amdgcn_global_load_lds(
      (const __attribute__((address_space(1))) void*)g,
      (__attribute__((address_space(3))) void*)l, 16, 0, 0);
}

__device__ __forceinline__ void ld8(const float* p, float (&v)[8]) {
  const float4* q = reinterpret_cast<const float4*>(p);
  float4 a = q[0], b = q[1];
  v[0] = a.x; v[1] = a.y; v[2] = a.z; v[3] = a.w;
  v[4] = b.x; v[5] = b.y; v[6] = b.z; v[7] = b.w;
}

// ---------------- main: fused feature-gen + MFMA GEMM ----------------
// Stage-once, free-run structure: ALL 72 weight fragment-entries (73.7 KB)
// staged into LDS in one prologue (9 x global_load_lds per thread), ONE
// __syncthreads, then a barrier-free G-loop — each wave runs through the
// 4 channel-groups independently (x prefetch is same-wave vmcnt-ordered,
// so no block sync is ever needed again). 512-thr blocks (8 waves x 32
// rows), 2 blocks/CU (LDS 2x73.7=147 KB <= 160 KB; VGPR capped 128 via
// __launch_bounds__(512,4)) -> 16 waves/CU, same as before but with 3 of
// 4 barriers removed and staging L2 traffic halved (512 vs 1024 blocks).
__global__ __launch_bounds__(512, 4) void kan_main(
    const float* __restrict__ x,
    const uint4* __restrict__ wfrag,
    const float* __restrict__ bias,
    float* __restrict__ out) {
  __shared__ uint4 wlds[4608];  // 4 G * 18 frag-entries * 64 lanes = 73728 B
  const int tid  = threadIdx.x;
  const int lane = tid & 63;
  const int wave = tid >> 6;
  const int m    = lane & 15;  // A row-in-tile; also C/D column (within half)
  const int quad = lane >> 4;  // A channel-octet selector; C/D row group
  const long rowbase = ((long)blockIdx.x * 8 + wave) * 32;

  // ---- prologue: stage ALL weights once (4608 uint4 = 9 per thread) ----
#pragma unroll
  for (int i = 0; i < 9; ++i)
    gl_lds16(wfrag + tid + i * 512, &wlds[tid + i * 512]);

  f32x4v a0A, a1A, a0B, a1B;
#pragma unroll
  for (int rr = 0; rr < 4; ++rr) {
    a0A[rr] = 0.f; a1A[rr] = 0.f; a0B[rr] = 0.f; a1B[rr] = 0.f;
  }

  // per-lane x base: tile A = rows rowbase+0..15, tile B = rows rowbase+16..31
  const float* xpA = x + (rowbase + m) * 128 + (long)quad * 8;
  const float* xpB = xpA + 16 * 128;

  float xa[8], xb[8];
  ld8(xpA, xa);
  ld8(xpB, xb);
  const float bv0 = bias[m];
  const float bv1 = bias[m + 16];

  __syncthreads();  // drains staging vmcnt (and x loads); the ONLY barrier

#pragma unroll 1
  for (int G = 0; G < 4; ++G) {
    // ---- consume xa/xb into compact per-G state (both row-tiles) ----
    bf16x8 sA, sB;
    float pA[8], rA[8], pB[8], rB[8];
    {
      float sv[8];
#pragma unroll
      for (int j = 0; j < 8; ++j) sv[j] = siluf(xa[j]);
      sA = packfrag(sv);
#pragma unroll
      for (int j = 0; j < 8; ++j) sv[j] = siluf(xb[j]);
      sB = packfrag(sv);
#pragma unroll
      for (int j = 0; j < 8; ++j) {
        float u = fmaf(xa[j], INVH, NC0H);
        pA[j] = fexp2(A2f * u * u);
        rA[j] = fexp2(B2f * u);
      }
#pragma unroll
      for (int j = 0; j < 8; ++j) {
        float u = fmaf(xb[j], INVH, NC0H);
        pB[j] = fexp2(A2f * u * u);
        rB[j] = fexp2(B2f * u);
      }
    }

    // ---- prefetch next G's x (same-wave dependency; hidden under the
    //      MFMA/t-loop, drained by the compiler's vmcnt at next use) ----
    if (G < 3) {
      ld8(xpA + (G + 1) * 32, xa);
      ld8(xpB + (G + 1) * 32, xb);
    }

    const uint4* wl = wlds + G * 1152 + lane;

    // ---- t = 0 : silu feature (both tiles share the weight frags) ----
    a0A = __builtin_amdgcn_mfma_f32_16x16x32_bf16(
        sA, __builtin_bit_cast(bf16x8, wl[0]), a0A, 0, 0, 0);
    a1A = __builtin_amdgcn_mfma_f32_16x16x32_bf16(
        sA, __builtin_bit_cast(bf16x8, wl[64]), a1A, 0, 0, 0);
    a0B = __builtin_amdgcn_mfma_f32_16x16x32_bf16(
        sB, __builtin_bit_cast(bf16x8, wl[0]), a0B, 0, 0, 0);
    a1B = __builtin_amdgcn_mfma_f32_16x16x32_bf16(
        sB, __builtin_bit_cast(bf16x8, wl[64]), a1B, 0, 0, 0);

    // ---- t = 1..8 : gaussian recurrence (g_k folded into weights) ----
#pragma unroll
    for (int t = 1; t <= 8; ++t) {
      bf16x8 c0 = __builtin_bit_cast(bf16x8, wl[t * 128]);
      bf16x8 c1 = __builtin_bit_cast(bf16x8, wl[t * 128 + 64]);
      bf16x8 fA = packfrag(pA);
      bf16x8 fB = packfrag(pB);
      a0A = __builtin_amdgcn_mfma_f32_16x16x32_bf16(fA, c0, a0A, 0, 0, 0);
      a1A = __builtin_amdgcn_mfma_f32_16x16x32_bf16(fA, c1, a1A, 0, 0, 0);
      a0B = __builtin_amdgcn_mfma_f32_16x16x32_bf16(fB, c0, a0B, 0, 0, 0);
      a1B = __builtin_amdgcn_mfma_f32_16x16x32_bf16(fB, c1, a1B, 0, 0, 0);
      if (t < 8) {
#pragma unroll
        for (int j = 0; j < 8; ++j) { pA[j] *= rA[j]; pB[j] *= rB[j]; }
      }
    }
  }

  // epilogue: C/D layout col = lane&15 (per half), row = quad*4 + reg
#pragma unroll
  for (int rr = 0; rr < 4; ++rr) {
    long row = rowbase + quad * 4 + rr;
    out[row * 32 + m]             = a0A[rr] + bv0;
    out[row * 32 + m + 16]        = a1A[rr] + bv1;
    out[(row + 16) * 32 + m]      = a0B[rr] + bv0;
    out[(row + 16) * 32 + m + 16] = a1B[rr] + bv1;
  }
}

extern "C" void kernel_launch(void* const* d_in, const int* in_sizes, int n_in,
                              void* d_out, int out_size, void* d_ws, size_t ws_size,
                              hipStream_t stream) {
  const float* x     = (const float*)d_in[0]; // (131072,128)
  const float* coeff = (const float*)d_in[1]; // (128,32,8)
  const float* bw    = (const float*)d_in[2]; // (128,32)
  const float* bb    = (const float*)d_in[3]; // (128,32)
  const float* ew    = (const float*)d_in[4]; // (128,32)

  uint4* wfrag = (uint4*)d_ws;                       // 72*64*16 = 73728 B
  float* bias  = (float*)((char*)d_ws + 73728);      // 32 floats

  kan_prep<<<19, 256, 0, stream>>>(coeff, bw, bb, ew, wfrag, bias);
  // 131072 rows / (8 waves * 32 rows) = 512 blocks of 512 threads
  kan_main<<<512, 512, 0, stream>>>(x, wfrag, bias, (float*)d_out);
}